// Round 1
// baseline (201.393 us; speedup 1.0000x reference)
//
#include <hip/hip_runtime.h>
#include <math.h>

#define B_  256
#define H_  256
#define C_  16384
#define S_  64
#define CS_ 32
#define K_  8
#define RET_ ((size_t)B_ * K_ * S_ * H_)   // 33,554,432 f32

// ---------------------------------------------------------------------------
// ws layout (4-byte units):
//   f32 [0..255]        qinv
//   f32 [256..16639]    einv
//   i32 @16640          mode (1 = is_compressed stored as 1-byte, 0 = int32)
//   i32 @16641..18688   top_idx (256*8)
// ---------------------------------------------------------------------------

// Detect storage width of is_compressed: if it is int32 (values 0/1), every
// byte at offset %4!=0 within the first C_ bytes is zero; if byte-bool, ~half
// of them are 1.
__global__ void detect_kernel(const unsigned char* __restrict__ ic, int* __restrict__ mode) {
    __shared__ int f;
    int t = threadIdx.x;
    if (t == 0) f = 0;
    __syncthreads();
    int any = 0;
    for (int i = t; i < C_; i += 256)
        if ((i & 3) != 0 && ic[i] != 0) any = 1;
    if (any) atomicOr(&f, 1);
    __syncthreads();
    if (t == 0) *mode = f;
}

// One wave per row; rows [0,256) = query, [256, 16640) = embeddings.
__global__ __launch_bounds__(256) void norms_kernel(const float* __restrict__ q,
                                                    const float* __restrict__ e,
                                                    float* __restrict__ qinv,
                                                    float* __restrict__ einv) {
    int wave = threadIdx.x >> 6, lane = threadIdx.x & 63;
    int row = blockIdx.x * 4 + wave;          // < 16640
    const float* src = (row < B_) ? q + (size_t)row * H_ : e + (size_t)(row - B_) * H_;
    float4 v = ((const float4*)src)[lane];    // 64 lanes * 4 = 256 = H_
    float s = v.x * v.x + v.y * v.y + v.z * v.z + v.w * v.w;
    #pragma unroll
    for (int d = 1; d < 64; d <<= 1) s += __shfl_xor(s, d);
    if (lane == 0) {
        float inv = 1.0f / fmaxf(sqrtf(s), 1e-8f);
        if (row < B_) qinv[row] = inv; else einv[row - B_] = inv;
    }
}

// sim[b][c] = (q_b . e_c) * qinv[b] * einv[c]
// 64x64 tile per block; 16x16 threads, 4x4 register tile; h staged in 4
// chunks of 64 into XOR-swizzled LDS (float4-aligned, conflict-light).
__global__ __launch_bounds__(256) void sim_kernel(const float* __restrict__ q,
                                                  const float* __restrict__ e,
                                                  const float* __restrict__ qinv,
                                                  const float* __restrict__ einv,
                                                  float* __restrict__ sim) {
    __shared__ float Qs[64 * 64];
    __shared__ float Es[64 * 64];
    const int t = threadIdx.x, tx = t & 15, ty = t >> 4;
    const int c0 = blockIdx.x * 64, b0 = blockIdx.y * 64;
    const float4* q4 = (const float4*)q;
    const float4* e4 = (const float4*)e;

    float acc[4][4] = {};

    for (int hc = 0; hc < 4; ++hc) {
        __syncthreads();
        #pragma unroll
        for (int i = 0; i < 4; ++i) {
            int f = t + 256 * i;
            int r = f >> 4, h4 = f & 15;
            int li = r * 64 + ((h4 ^ (r & 15)) << 2);       // swizzled f4 slot
            *(float4*)&Qs[li] = q4[(size_t)(b0 + r) * 64 + hc * 16 + h4];
            *(float4*)&Es[li] = e4[(size_t)(c0 + r) * 64 + hc * 16 + h4];
        }
        __syncthreads();
        #pragma unroll
        for (int h4 = 0; h4 < 16; ++h4) {
            float4 qv[4], ev[4];
            #pragma unroll
            for (int i = 0; i < 4; ++i) {                   // row = ty + 16i, (row&15)==ty
                qv[i] = *(const float4*)&Qs[(ty + 16 * i) * 64 + ((h4 ^ ty) << 2)];
            }
            #pragma unroll
            for (int j = 0; j < 4; ++j) {                   // row = tx + 16j, (row&15)==tx
                ev[j] = *(const float4*)&Es[(tx + 16 * j) * 64 + ((h4 ^ tx) << 2)];
            }
            #pragma unroll
            for (int i = 0; i < 4; ++i)
                #pragma unroll
                for (int j = 0; j < 4; ++j) {
                    acc[i][j] = fmaf(qv[i].x, ev[j].x, acc[i][j]);
                    acc[i][j] = fmaf(qv[i].y, ev[j].y, acc[i][j]);
                    acc[i][j] = fmaf(qv[i].z, ev[j].z, acc[i][j]);
                    acc[i][j] = fmaf(qv[i].w, ev[j].w, acc[i][j]);
                }
        }
    }

    #pragma unroll
    for (int i = 0; i < 4; ++i) {
        int b = b0 + ty + 16 * i;
        float qi = qinv[b];
        #pragma unroll
        for (int j = 0; j < 4; ++j) {
            int c = c0 + tx + 16 * j;
            sim[(size_t)b * C_ + c] = acc[i][j] * qi * einv[c];
        }
    }
}

// Per-row top-8 with JAX tie-break (lower index wins ties).
__global__ __launch_bounds__(256) void topk_kernel(const float* __restrict__ sim,
                                                   float* __restrict__ out_scores,
                                                   int* __restrict__ top_idx) {
    __shared__ float ss[2048];
    __shared__ int   si[2048];
    const int t = threadIdx.x, b = blockIdx.x;
    const float* row = sim + (size_t)b * C_;

    float s[8]; int id[8];
    #pragma unroll
    for (int k = 0; k < 8; ++k) { s[k] = -INFINITY; id[k] = 0x7fffffff; }
    for (int i = 0; i < 64; ++i) {
        int c = i * 256 + t;
        float v = row[c];
        if (v > s[7] || (v == s[7] && c < id[7])) {
            s[7] = v; id[7] = c;
            #pragma unroll
            for (int k = 7; k > 0; --k) {
                if (s[k] > s[k-1] || (s[k] == s[k-1] && id[k] < id[k-1])) {
                    float tv = s[k]; s[k] = s[k-1]; s[k-1] = tv;
                    int ti = id[k]; id[k] = id[k-1]; id[k-1] = ti;
                }
            }
        }
    }
    #pragma unroll
    for (int k = 0; k < 8; ++k) { ss[t * 8 + k] = s[k]; si[t * 8 + k] = id[k]; }
    __syncthreads();

    if (t < 64) {   // single wave does 8 argmax passes over the 2048 partials
        for (int j = 0; j < 8; ++j) {
            float bs = -INFINITY; int bi = 0x7fffffff, bp = -1;
            for (int m = 0; m < 32; ++m) {
                int p = t + m * 64;
                float v = ss[p];
                if (v > bs || (v == bs && si[p] < bi)) { bs = v; bi = si[p]; bp = p; }
            }
            #pragma unroll
            for (int d = 1; d < 64; d <<= 1) {
                float os = __shfl_xor(bs, d);
                int   oi = __shfl_xor(bi, d);
                int   op = __shfl_xor(bp, d);
                if (os > bs || (os == bs && oi < bi)) { bs = os; bi = oi; bp = op; }
            }
            ss[bp] = -INFINITY;                 // all lanes, same addr/value; in-wave DS order
            if (t == 0) { out_scores[b * K_ + j] = bs; top_idx[b * K_ + j] = bi; }
        }
    }
}

// out[b][j][s][:] = flag ? (s<CS ? comp[c][s][:] : 0) : epi[c][s][:]
// One block = one (b,j) x 4 consecutive s-rows; float4 fully coalesced.
__global__ __launch_bounds__(256) void gather_kernel(const float* __restrict__ epi,
                                                     const float* __restrict__ comp,
                                                     const void* __restrict__ icp,
                                                     const int* __restrict__ top_idx,
                                                     const int* __restrict__ mode,
                                                     float* __restrict__ out) {
    const int blk = blockIdx.x;
    const int bj = blk >> 4, sg = blk & 15;
    const int c = top_idx[bj];
    const int m = *mode;
    const int flag = m ? (((const unsigned char*)icp)[c] != 0)
                       : (((const int*)icp)[c] != 0);
    const int t = threadIdx.x;
    const int s = sg * 4 + (t >> 6), h4 = t & 63;
    float4 v;
    if (flag) {
        if (s < CS_) v = ((const float4*)comp)[((size_t)c * CS_ + s) * 64 + h4];
        else         v = make_float4(0.f, 0.f, 0.f, 0.f);
    } else {
        v = ((const float4*)epi)[((size_t)c * S_ + s) * 64 + h4];
    }
    ((float4*)out)[((size_t)bj * S_ + s) * 64 + h4] = v;
}

extern "C" void kernel_launch(void* const* d_in, const int* in_sizes, int n_in,
                              void* d_out, int out_size, void* d_ws, size_t ws_size,
                              hipStream_t stream) {
    const float* query = (const float*)d_in[0];
    const float* emb   = (const float*)d_in[1];
    const float* epi   = (const float*)d_in[2];
    const float* comp  = (const float*)d_in[3];
    const void*  icp   = d_in[4];
    float* out = (float*)d_out;

    float* wsf    = (float*)d_ws;
    float* qinv   = wsf;
    float* einv   = wsf + 256;
    int*   mode   = (int*)(wsf + 16640);
    int*   topidx = mode + 1;

    float* simbuf     = out;          // 16.8 MB staged in retrieved region, overwritten by gather
    float* out_scores = out + RET_;

    detect_kernel<<<1, 256, 0, stream>>>((const unsigned char*)icp, mode);
    norms_kernel<<<(B_ + C_) / 4, 256, 0, stream>>>(query, emb, qinv, einv);
    sim_kernel<<<dim3(C_ / 64, B_ / 64), 256, 0, stream>>>(query, emb, qinv, einv, simbuf);
    topk_kernel<<<B_, 256, 0, stream>>>(simbuf, out_scores, topidx);
    gather_kernel<<<B_ * K_ * (S_ / 4), 256, 0, stream>>>(epi, comp, icp, topidx, mode, out);
}

// Round 2
// 199.120 us; speedup vs baseline: 1.0114x; 1.0114x over previous
//
#include <hip/hip_runtime.h>
#include <math.h>

#define B_  256
#define H_  256
#define C_  16384
#define S_  64
#define CS_ 32
#define K_  8
#define RET_ ((size_t)B_ * K_ * S_ * H_)   // 33,554,432 f32

typedef __attribute__((ext_vector_type(8))) short short8v;
typedef __attribute__((ext_vector_type(4))) float f32x4;

// ws layout (f32 units): qinv[0..255], einv[256..16639], mode@16640, topidx@16641..
// cand[256*32] lives in d_out scratch at f32 offset 8M (beyond sim's 4.19M,
// read by rescore before gather overwrites it).

__device__ inline unsigned short f2bf(float f) {           // RTNE f32->bf16
    unsigned u = __builtin_bit_cast(unsigned, f);
    unsigned r = u + 0x7fffu + ((u >> 16) & 1u);
    return (unsigned short)(r >> 16);
}

// blocks 0..4159: row inverse-norms (1 wave per row). block 4160: detect
// is_compressed storage width (byte-bool vs int32).
__global__ __launch_bounds__(256) void prep_kernel(const float* __restrict__ q,
                                                   const float* __restrict__ e,
                                                   const unsigned char* __restrict__ ic,
                                                   float* __restrict__ qinv,
                                                   float* __restrict__ einv,
                                                   int* __restrict__ mode) {
    if (blockIdx.x == 4160) {
        __shared__ int f;
        int t = threadIdx.x;
        if (t == 0) f = 0;
        __syncthreads();
        int any = 0;
        for (int i = t; i < C_; i += 256)
            if ((i & 3) != 0 && ic[i] != 0) any = 1;
        if (any) atomicOr(&f, 1);
        __syncthreads();
        if (t == 0) *mode = f;
        return;
    }
    int wave = threadIdx.x >> 6, lane = threadIdx.x & 63;
    int row = blockIdx.x * 4 + wave;          // < 16640
    const float* src = (row < B_) ? q + (size_t)row * H_ : e + (size_t)(row - B_) * H_;
    float4 v = ((const float4*)src)[lane];
    float s = v.x * v.x + v.y * v.y + v.z * v.z + v.w * v.w;
    #pragma unroll
    for (int d = 1; d < 64; d <<= 1) s += __shfl_xor(s, d);
    if (lane == 0) {
        float inv = 1.0f / fmaxf(sqrtf(s), 1e-8f);
        if (row < B_) qinv[row] = inv; else einv[row - B_] = inv;
    }
}

// sim[b][c] via bf16 MFMA (f32 accum). Block tile 64b x 64c, BK=32, 4 waves
// in 2x2, each wave 32x32 (2x2 frags of 16x16x32).
#define LSTR 40   // bf16 row stride (32 + 8 pad -> 80B, conflict-light)
__global__ __launch_bounds__(256) void sim_mfma_kernel(const float* __restrict__ q,
                                                       const float* __restrict__ e,
                                                       const float* __restrict__ qinv,
                                                       const float* __restrict__ einv,
                                                       float* __restrict__ sim) {
    __shared__ unsigned short Qs[64 * LSTR];
    __shared__ unsigned short Es[64 * LSTR];
    const int t = threadIdx.x, lane = t & 63, wv = t >> 6;
    const int wm = wv >> 1, wn = wv & 1;
    const int c0 = blockIdx.x * 64, b0 = blockIdx.y * 64;
    const int srow = t >> 2, shg = t & 3;              // staging: row, 8-h group
    const float4* q4 = (const float4*)q;
    const float4* e4 = (const float4*)e;

    f32x4 acc[2][2];
    #pragma unroll
    for (int i = 0; i < 2; ++i)
        #pragma unroll
        for (int j = 0; j < 2; ++j) acc[i][j] = (f32x4){0.f, 0.f, 0.f, 0.f};

    for (int hc = 0; hc < 8; ++hc) {
        __syncthreads();
        float4 a0 = q4[(size_t)(b0 + srow) * 64 + hc * 8 + shg * 2];
        float4 a1 = q4[(size_t)(b0 + srow) * 64 + hc * 8 + shg * 2 + 1];
        float4 c0v = e4[(size_t)(c0 + srow) * 64 + hc * 8 + shg * 2];
        float4 c1v = e4[(size_t)(c0 + srow) * 64 + hc * 8 + shg * 2 + 1];
        short8v qa, ea;
        qa[0] = (short)f2bf(a0.x); qa[1] = (short)f2bf(a0.y);
        qa[2] = (short)f2bf(a0.z); qa[3] = (short)f2bf(a0.w);
        qa[4] = (short)f2bf(a1.x); qa[5] = (short)f2bf(a1.y);
        qa[6] = (short)f2bf(a1.z); qa[7] = (short)f2bf(a1.w);
        ea[0] = (short)f2bf(c0v.x); ea[1] = (short)f2bf(c0v.y);
        ea[2] = (short)f2bf(c0v.z); ea[3] = (short)f2bf(c0v.w);
        ea[4] = (short)f2bf(c1v.x); ea[5] = (short)f2bf(c1v.y);
        ea[6] = (short)f2bf(c1v.z); ea[7] = (short)f2bf(c1v.w);
        *(short8v*)&Qs[srow * LSTR + shg * 8] = qa;
        *(short8v*)&Es[srow * LSTR + shg * 8] = ea;
        __syncthreads();

        short8v afr[2], bfr[2];
        #pragma unroll
        for (int mi = 0; mi < 2; ++mi)
            afr[mi] = *(short8v*)&Qs[(wm * 32 + mi * 16 + (lane & 15)) * LSTR + (lane >> 4) * 8];
        #pragma unroll
        for (int ni = 0; ni < 2; ++ni)
            bfr[ni] = *(short8v*)&Es[(wn * 32 + ni * 16 + (lane & 15)) * LSTR + (lane >> 4) * 8];
        #pragma unroll
        for (int mi = 0; mi < 2; ++mi)
            #pragma unroll
            for (int ni = 0; ni < 2; ++ni)
                acc[mi][ni] = __builtin_amdgcn_mfma_f32_16x16x32_bf16(
                    afr[mi], bfr[ni], acc[mi][ni], 0, 0, 0);
    }

    #pragma unroll
    for (int mi = 0; mi < 2; ++mi) {
        #pragma unroll
        for (int j = 0; j < 4; ++j) {
            int b = b0 + wm * 32 + mi * 16 + (lane >> 4) * 4 + j;
            float qi = qinv[b];
            #pragma unroll
            for (int ni = 0; ni < 2; ++ni) {
                int c = c0 + wn * 32 + ni * 16 + (lane & 15);
                sim[(size_t)b * C_ + c] = acc[mi][ni][j] * qi * einv[c];
            }
        }
    }
}

// Coarse top-32 per row from MFMA sims (per-thread top-4 -> 1024 cands ->
// 32 argmax passes by one wave). Tie-break: lower index.
__global__ __launch_bounds__(256) void topk32_kernel(const float* __restrict__ sim,
                                                     int* __restrict__ cand) {
    __shared__ float ss[1024];
    __shared__ int   si[1024];
    const int t = threadIdx.x, b = blockIdx.x;
    const float* row = sim + (size_t)b * C_;

    float s[4]; int id[4];
    #pragma unroll
    for (int k = 0; k < 4; ++k) { s[k] = -INFINITY; id[k] = 0x7fffffff; }
    for (int i = 0; i < 64; ++i) {
        int c = i * 256 + t;
        float v = row[c];
        if (v > s[3] || (v == s[3] && c < id[3])) {
            s[3] = v; id[3] = c;
            #pragma unroll
            for (int k = 3; k > 0; --k) {
                if (s[k] > s[k-1] || (s[k] == s[k-1] && id[k] < id[k-1])) {
                    float tv = s[k]; s[k] = s[k-1]; s[k-1] = tv;
                    int ti = id[k]; id[k] = id[k-1]; id[k-1] = ti;
                }
            }
        }
    }
    #pragma unroll
    for (int k = 0; k < 4; ++k) { ss[t * 4 + k] = s[k]; si[t * 4 + k] = id[k]; }
    __syncthreads();

    if (t < 64) {
        for (int p = 0; p < 32; ++p) {
            float bs = -INFINITY; int bi = 0x7fffffff, bp = -1;
            for (int m = 0; m < 16; ++m) {
                int q = t + m * 64;
                float v = ss[q];
                if (v > bs || (v == bs && si[q] < bi)) { bs = v; bi = si[q]; bp = q; }
            }
            #pragma unroll
            for (int d = 1; d < 64; d <<= 1) {
                float os = __shfl_xor(bs, d);
                int   oi = __shfl_xor(bi, d);
                int   op = __shfl_xor(bp, d);
                if (os > bs || (os == bs && oi < bi)) { bs = os; bi = oi; bp = op; }
            }
            ss[bp] = -INFINITY;
            if (t == 0) cand[b * 32 + p] = bi;
        }
    }
}

// Exact f32 rescore of the 32 candidates + final top-8 (JAX tie-break).
__global__ __launch_bounds__(256) void rescore_kernel(const float* __restrict__ q,
                                                      const float* __restrict__ e,
                                                      const float* __restrict__ qinv,
                                                      const float* __restrict__ einv,
                                                      const int* __restrict__ cand,
                                                      float* __restrict__ out_scores,
                                                      int* __restrict__ top_idx) {
    __shared__ float rs[32];
    __shared__ int   ri[32];
    const int t = threadIdx.x, b = blockIdx.x;
    const int wv = t >> 6, lane = t & 63;
    float4 qv = ((const float4*)q)[(size_t)b * 64 + lane];
    #pragma unroll
    for (int m = wv; m < 32; m += 4) {
        int idx = cand[b * 32 + m];
        float4 ev = ((const float4*)e)[(size_t)idx * 64 + lane];
        float s = qv.x * ev.x + qv.y * ev.y + qv.z * ev.z + qv.w * ev.w;
        #pragma unroll
        for (int d = 1; d < 64; d <<= 1) s += __shfl_xor(s, d);
        if (lane == 0) { rs[m] = s; ri[m] = idx; }
    }
    __syncthreads();
    if (t < 64) {
        float val; int idx, slot;
        if (t < 32) { idx = ri[t]; val = rs[t] * qinv[b] * einv[idx]; slot = t; }
        else        { idx = 0x7fffffff; val = -INFINITY; slot = -1; }
        for (int p = 0; p < 8; ++p) {
            float bs = val; int bi = idx, bsl = slot;
            #pragma unroll
            for (int d = 1; d < 64; d <<= 1) {
                float os = __shfl_xor(bs, d);
                int   oi = __shfl_xor(bi, d);
                int   osl = __shfl_xor(bsl, d);
                if (os > bs || (os == bs && oi < bi)) { bs = os; bi = oi; bsl = osl; }
            }
            if (t == 0) { out_scores[b * K_ + p] = bs; top_idx[b * K_ + p] = bi; }
            if (slot == bsl) val = -INFINITY;
        }
    }
}

// One block per (b,j): contiguous 64KB read + 64KB write.
__global__ __launch_bounds__(256) void gather_kernel(const float* __restrict__ epi,
                                                     const float* __restrict__ comp,
                                                     const void* __restrict__ icp,
                                                     const int* __restrict__ top_idx,
                                                     const int* __restrict__ mode,
                                                     float* __restrict__ out) {
    const int bj = blockIdx.x;
    const int c = top_idx[bj];
    const int m = *mode;
    const int flag = m ? (((const unsigned char*)icp)[c] != 0)
                       : (((const int*)icp)[c] != 0);
    float4* o4 = (float4*)out + (size_t)bj * 4096;
    if (!flag) {
        const float4* s4 = (const float4*)epi + (size_t)c * 4096;
        #pragma unroll 4
        for (int i = threadIdx.x; i < 4096; i += 256) o4[i] = s4[i];
    } else {
        const float4* s4 = (const float4*)comp + (size_t)c * 2048;
        #pragma unroll 4
        for (int i = threadIdx.x; i < 2048; i += 256) o4[i] = s4[i];
        const float4 z = make_float4(0.f, 0.f, 0.f, 0.f);
        #pragma unroll 4
        for (int i = 2048 + threadIdx.x; i < 4096; i += 256) o4[i] = z;
    }
}

extern "C" void kernel_launch(void* const* d_in, const int* in_sizes, int n_in,
                              void* d_out, int out_size, void* d_ws, size_t ws_size,
                              hipStream_t stream) {
    const float* query = (const float*)d_in[0];
    const float* emb   = (const float*)d_in[1];
    const float* epi   = (const float*)d_in[2];
    const float* comp  = (const float*)d_in[3];
    const void*  icp   = d_in[4];
    float* out = (float*)d_out;

    float* wsf    = (float*)d_ws;
    float* qinv   = wsf;
    float* einv   = wsf + 256;
    int*   mode   = (int*)(wsf + 16640);
    int*   topidx = mode + 1;

    float* simbuf     = out;                    // 16.8 MB scratch, overwritten by gather
    int*   cand       = (int*)(out + 8000000);  // 32 KB scratch, read before gather
    float* out_scores = out + RET_;

    prep_kernel<<<4161, 256, 0, stream>>>(query, emb, (const unsigned char*)icp,
                                          qinv, einv, mode);
    sim_mfma_kernel<<<dim3(C_ / 64, B_ / 64), 256, 0, stream>>>(query, emb, qinv, einv, simbuf);
    topk32_kernel<<<B_, 256, 0, stream>>>(simbuf, cand);
    rescore_kernel<<<B_, 256, 0, stream>>>(query, emb, qinv, einv, cand, out_scores, topidx);
    gather_kernel<<<B_ * K_, 256, 0, stream>>>(epi, comp, icp, topidx, mode, out);
}

// Round 3
// 125.155 us; speedup vs baseline: 1.6092x; 1.5910x over previous
//
#include <hip/hip_runtime.h>
#include <math.h>

#define B_  256
#define H_  256
#define C_  16384
#define S_  64
#define CS_ 32
#define K_  8
#define EPS 1e-8f
#define RET_ ((size_t)B_ * K_ * S_ * H_)   // 33,554,432 f32

typedef __attribute__((ext_vector_type(8))) short short8v;
typedef __attribute__((ext_vector_type(4))) float f32x4;

// ws layout (i32 units): mode@0, topidx@1..2048
// simbuf (16.8 MB) lives in d_out[0..4194304), read by select before gather
// overwrites; out_scores at d_out + RET_.

__device__ inline unsigned short f2bf(float f) {           // RTNE f32->bf16
    unsigned u = __builtin_bit_cast(unsigned, f);
    unsigned r = u + 0x7fffu + ((u >> 16) & 1u);
    return (unsigned short)(r >> 16);
}
__device__ inline unsigned ordf(float f) {                 // order-preserving f32->u32
    unsigned u = __builtin_bit_cast(unsigned, f);
    return u ^ ((u >> 31) ? 0xFFFFFFFFu : 0x80000000u);
}

// sim[b][c] = bf16dot(q_b, e_c) * einv[c]   (qinv dropped: rank-invariant)
// Block tile 64b x 64c, BK=32, 4 waves 2x2, wave = 32x32 (2x2 frags 16x16x32).
// einv computed in-block from the staged E tiles.
#define LSTR 40
__global__ __launch_bounds__(256) void sim_mfma_kernel(const float* __restrict__ q,
                                                       const float* __restrict__ e,
                                                       float* __restrict__ sim) {
    __shared__ unsigned short Qs[64 * LSTR];
    __shared__ unsigned short Es[64 * LSTR];
    __shared__ float einv_s[64];
    const int t = threadIdx.x, lane = t & 63, wv = t >> 6;
    const int wm = wv >> 1, wn = wv & 1;
    const int c0 = blockIdx.x * 64, b0 = blockIdx.y * 64;
    const int srow = t >> 2, shg = t & 3;
    const float4* q4 = (const float4*)q;
    const float4* e4 = (const float4*)e;

    float esq = 0.f;
    f32x4 acc[2][2];
    #pragma unroll
    for (int i = 0; i < 2; ++i)
        #pragma unroll
        for (int j = 0; j < 2; ++j) acc[i][j] = (f32x4){0.f, 0.f, 0.f, 0.f};

    for (int hc = 0; hc < 8; ++hc) {
        __syncthreads();
        float4 a0 = q4[(size_t)(b0 + srow) * 64 + hc * 8 + shg * 2];
        float4 a1 = q4[(size_t)(b0 + srow) * 64 + hc * 8 + shg * 2 + 1];
        float4 e0 = e4[(size_t)(c0 + srow) * 64 + hc * 8 + shg * 2];
        float4 e1 = e4[(size_t)(c0 + srow) * 64 + hc * 8 + shg * 2 + 1];
        esq += e0.x * e0.x + e0.y * e0.y + e0.z * e0.z + e0.w * e0.w
             + e1.x * e1.x + e1.y * e1.y + e1.z * e1.z + e1.w * e1.w;
        short8v qa, ea;
        qa[0] = (short)f2bf(a0.x); qa[1] = (short)f2bf(a0.y);
        qa[2] = (short)f2bf(a0.z); qa[3] = (short)f2bf(a0.w);
        qa[4] = (short)f2bf(a1.x); qa[5] = (short)f2bf(a1.y);
        qa[6] = (short)f2bf(a1.z); qa[7] = (short)f2bf(a1.w);
        ea[0] = (short)f2bf(e0.x); ea[1] = (short)f2bf(e0.y);
        ea[2] = (short)f2bf(e0.z); ea[3] = (short)f2bf(e0.w);
        ea[4] = (short)f2bf(e1.x); ea[5] = (short)f2bf(e1.y);
        ea[6] = (short)f2bf(e1.z); ea[7] = (short)f2bf(e1.w);
        *(short8v*)&Qs[srow * LSTR + shg * 8] = qa;
        *(short8v*)&Es[srow * LSTR + shg * 8] = ea;
        __syncthreads();

        short8v afr[2], bfr[2];
        #pragma unroll
        for (int mi = 0; mi < 2; ++mi)
            afr[mi] = *(short8v*)&Qs[(wm * 32 + mi * 16 + (lane & 15)) * LSTR + (lane >> 4) * 8];
        #pragma unroll
        for (int ni = 0; ni < 2; ++ni)
            bfr[ni] = *(short8v*)&Es[(wn * 32 + ni * 16 + (lane & 15)) * LSTR + (lane >> 4) * 8];
        #pragma unroll
        for (int mi = 0; mi < 2; ++mi)
            #pragma unroll
            for (int ni = 0; ni < 2; ++ni)
                acc[mi][ni] = __builtin_amdgcn_mfma_f32_16x16x32_bf16(
                    afr[mi], bfr[ni], acc[mi][ni], 0, 0, 0);
    }

    esq += __shfl_xor(esq, 1);
    esq += __shfl_xor(esq, 2);
    if (shg == 0) einv_s[srow] = 1.0f / fmaxf(sqrtf(esq), EPS);
    __syncthreads();

    #pragma unroll
    for (int mi = 0; mi < 2; ++mi) {
        #pragma unroll
        for (int j = 0; j < 4; ++j) {
            int b = b0 + wm * 32 + mi * 16 + (lane >> 4) * 4 + j;
            #pragma unroll
            for (int ni = 0; ni < 2; ++ni) {
                int cc = wn * 32 + ni * 16 + (lane & 15);
                sim[(size_t)b * C_ + c0 + cc] = acc[mi][ni][j] * einv_s[cc];
            }
        }
    }
}

// Blocks 0..255: per-row coarse top-32 (per-thread top-4 -> bitonic sort 1024)
// + exact f32 rescore + final top-8 (JAX tie-break). Block 256: detect mode.
__global__ __launch_bounds__(256) void select_kernel(const float* __restrict__ q,
                                                     const float* __restrict__ e,
                                                     const float* __restrict__ sim,
                                                     const unsigned* __restrict__ icw,
                                                     int* __restrict__ mode,
                                                     float* __restrict__ out_scores,
                                                     int* __restrict__ top_idx) {
    const int t = threadIdx.x, b = blockIdx.x;
    if (b == 256) {     // is_compressed stored as byte-bool (1) or int32 (0)?
        __shared__ int f;
        if (t == 0) f = 0;
        __syncthreads();
        int any = 0;
        for (int i = t; i < 4096; i += 256)
            if (icw[i] & 0xFFFFFF00u) any = 1;
        if (any) atomicOr(&f, 1);
        __syncthreads();
        if (t == 0) *mode = f;
        return;
    }

    __shared__ unsigned long long keys[1024];
    __shared__ float rs[32];
    __shared__ int   ri[32];
    const float* row = sim + (size_t)b * C_;

    // per-thread top-4 over 64 strided (coalesced) values
    float s[4]; int id[4];
    #pragma unroll
    for (int k = 0; k < 4; ++k) { s[k] = -INFINITY; id[k] = 0x7fffffff; }
    for (int i = 0; i < 64; ++i) {
        int c = i * 256 + t;
        float v = row[c];
        if (v > s[3] || (v == s[3] && c < id[3])) {
            s[3] = v; id[3] = c;
            #pragma unroll
            for (int k = 3; k > 0; --k) {
                if (s[k] > s[k-1] || (s[k] == s[k-1] && id[k] < id[k-1])) {
                    float tv = s[k]; s[k] = s[k-1]; s[k-1] = tv;
                    int ti = id[k]; id[k] = id[k-1]; id[k-1] = ti;
                }
            }
        }
    }
    #pragma unroll
    for (int k = 0; k < 4; ++k)
        keys[t * 4 + k] = ((unsigned long long)ordf(s[k]) << 32)
                        | (unsigned)(0xFFFFFFFFu - (unsigned)id[k]);
    __syncthreads();

    // bitonic sort ascending; top-32 ends at keys[992..1023]
    for (int k = 2; k <= 1024; k <<= 1) {
        for (int j = k >> 1; j > 0; j >>= 1) {
            #pragma unroll
            for (int base = 0; base < 1024; base += 256) {
                int i = base + t, l = i ^ j;
                if (l > i) {
                    unsigned long long a = keys[i], bb = keys[l];
                    bool up = ((i & k) == 0);
                    if ((a > bb) == up) { keys[i] = bb; keys[l] = a; }
                }
            }
            __syncthreads();
        }
    }

    // exact f32 rescore of the 32 candidates; 4 waves x 8 candidates
    const int wv = t >> 6, lane = t & 63;
    float4 qv = ((const float4*)q)[(size_t)b * 64 + lane];
    float qsq = qv.x * qv.x + qv.y * qv.y + qv.z * qv.z + qv.w * qv.w;
    #pragma unroll
    for (int d = 1; d < 64; d <<= 1) qsq += __shfl_xor(qsq, d);
    float qi = 1.0f / fmaxf(sqrtf(qsq), EPS);

    for (int m = wv; m < 32; m += 4) {
        unsigned long long key = keys[1023 - m];
        int idx = (int)(0xFFFFFFFFu - (unsigned)(key & 0xFFFFFFFFull));
        float4 ev = ((const float4*)e)[(size_t)idx * 64 + lane];
        float dot = qv.x * ev.x + qv.y * ev.y + qv.z * ev.z + qv.w * ev.w;
        float ss  = ev.x * ev.x + ev.y * ev.y + ev.z * ev.z + ev.w * ev.w;
        #pragma unroll
        for (int d = 1; d < 64; d <<= 1) {
            dot += __shfl_xor(dot, d);
            ss  += __shfl_xor(ss, d);
        }
        if (lane == 0) {
            rs[m] = dot * qi * (1.0f / fmaxf(sqrtf(ss), EPS));
            ri[m] = idx;
        }
    }
    __syncthreads();

    if (t < 64) {       // final top-8 of 32 (score desc, idx asc)
        float val; int idx, slot;
        if (t < 32) { val = rs[t]; idx = ri[t]; slot = t; }
        else        { val = -INFINITY; idx = 0x7fffffff; slot = -1; }
        for (int p = 0; p < 8; ++p) {
            float bs = val; int bi = idx, bsl = slot;
            #pragma unroll
            for (int d = 1; d < 64; d <<= 1) {
                float os = __shfl_xor(bs, d);
                int   oi = __shfl_xor(bi, d);
                int   osl = __shfl_xor(bsl, d);
                if (os > bs || (os == bs && oi < bi)) { bs = os; bi = oi; bsl = osl; }
            }
            if (t == 0) { out_scores[b * K_ + p] = bs; top_idx[b * K_ + p] = bi; }
            if (slot == bsl) val = -INFINITY;
        }
    }
}

// One block per (b,j): contiguous 64KB read + 64KB write, nontemporal.
__global__ __launch_bounds__(256) void gather_kernel(const float* __restrict__ epi,
                                                     const float* __restrict__ comp,
                                                     const void* __restrict__ icp,
                                                     const int* __restrict__ top_idx,
                                                     const int* __restrict__ mode,
                                                     float* __restrict__ out) {
    const int bj = blockIdx.x;
    const int c = top_idx[bj];
    const int m = *mode;
    const int flag = m ? (((const unsigned char*)icp)[c] != 0)
                       : (((const int*)icp)[c] != 0);
    f32x4* o4 = (f32x4*)out + (size_t)bj * 4096;
    if (!flag) {
        const f32x4* s4 = (const f32x4*)epi + (size_t)c * 4096;
        #pragma unroll 4
        for (int i = threadIdx.x; i < 4096; i += 256)
            __builtin_nontemporal_store(__builtin_nontemporal_load(s4 + i), o4 + i);
    } else {
        const f32x4* s4 = (const f32x4*)comp + (size_t)c * 2048;
        #pragma unroll 4
        for (int i = threadIdx.x; i < 2048; i += 256)
            __builtin_nontemporal_store(__builtin_nontemporal_load(s4 + i), o4 + i);
        const f32x4 z = (f32x4){0.f, 0.f, 0.f, 0.f};
        #pragma unroll 4
        for (int i = 2048 + threadIdx.x; i < 4096; i += 256)
            __builtin_nontemporal_store(z, o4 + i);
    }
}

extern "C" void kernel_launch(void* const* d_in, const int* in_sizes, int n_in,
                              void* d_out, int out_size, void* d_ws, size_t ws_size,
                              hipStream_t stream) {
    const float* query = (const float*)d_in[0];
    const float* emb   = (const float*)d_in[1];
    const float* epi   = (const float*)d_in[2];
    const float* comp  = (const float*)d_in[3];
    const void*  icp   = d_in[4];
    float* out = (float*)d_out;

    int* mode   = (int*)d_ws;
    int* topidx = mode + 1;

    float* simbuf     = out;       // 16.8 MB scratch, overwritten by gather
    float* out_scores = out + RET_;

    sim_mfma_kernel<<<dim3(C_ / 64, B_ / 64), 256, 0, stream>>>(query, emb, simbuf);
    select_kernel<<<257, 256, 0, stream>>>(query, emb, simbuf, (const unsigned*)icp,
                                           mode, out_scores, topidx);
    gather_kernel<<<B_ * K_, 256, 0, stream>>>(epi, comp, icp, topidx, mode, out);
}